// Round 8
// baseline (962.008 us; speedup 1.0000x reference)
//
#include <hip/hip_runtime.h>

// Problem constants (fixed shape)
#define M_DIM 8192   // B*S = 2*4096
#define N_DIM 4096   // D_OUT
#define K_DIM 4096   // D_IN

typedef __attribute__((ext_vector_type(4))) float f32x4;
using short8 = __attribute__((ext_vector_type(8))) short;

// ---------------------------------------------------------------------------
// Numerics helpers
// ---------------------------------------------------------------------------

__device__ __forceinline__ float e4m3_rt(float f) {
    float a = fabsf(f);
    int e = (int)((__float_as_uint(a) >> 23)) - 127;
    if (e < -6) e = -6;
    float q    = __uint_as_float((unsigned)(e - 3 + 127) << 23);
    float qinv = __uint_as_float((unsigned)(3 - e + 127) << 23);
    float r = rintf(a * qinv) * q;
    if (r > 448.0f) r = 448.0f;
    return copysignf(r, f);
}

__device__ __forceinline__ unsigned short f2bf(float f) {
    unsigned u = __float_as_uint(f);
    u += 0x7FFFu + ((u >> 16) & 1u);
    return (unsigned short)(u >> 16);
}

#define BAR()   asm volatile("s_barrier" ::: "memory")
#define WAITK() do { asm volatile("s_waitcnt lgkmcnt(0)" ::: "memory"); \
                     __builtin_amdgcn_sched_barrier(0); } while (0)

// ---------------------------------------------------------------------------
// Conversion pre-passes (unchanged)
// ---------------------------------------------------------------------------

__global__ void cvt_x_kernel(const float* __restrict__ in,
                             unsigned short* __restrict__ outp, long n8) {
    long stride = (long)gridDim.x * blockDim.x;
    for (long i = (long)blockIdx.x * blockDim.x + threadIdx.x; i < n8; i += stride) {
        const float4* p = (const float4*)(in + i * 8);
        float4 v0 = p[0], v1 = p[1];
        uint4 o;
        o.x = (unsigned)f2bf(v0.x) | ((unsigned)f2bf(v0.y) << 16);
        o.y = (unsigned)f2bf(v0.z) | ((unsigned)f2bf(v0.w) << 16);
        o.z = (unsigned)f2bf(v1.x) | ((unsigned)f2bf(v1.y) << 16);
        o.w = (unsigned)f2bf(v1.z) | ((unsigned)f2bf(v1.w) << 16);
        *(uint4*)(outp + i * 8) = o;
    }
}

__global__ void cvt_w_kernel(const float* __restrict__ in,
                             unsigned short* __restrict__ outp, long n8) {
    long stride = (long)gridDim.x * blockDim.x;
    for (long i = (long)blockIdx.x * blockDim.x + threadIdx.x; i < n8; i += stride) {
        const float4* p = (const float4*)(in + i * 8);
        float4 v0 = p[0], v1 = p[1];
        uint4 o;
        o.x = (unsigned)f2bf(e4m3_rt(v0.x)) | ((unsigned)f2bf(e4m3_rt(v0.y)) << 16);
        o.y = (unsigned)f2bf(e4m3_rt(v0.z)) | ((unsigned)f2bf(e4m3_rt(v0.w)) << 16);
        o.z = (unsigned)f2bf(e4m3_rt(v1.x)) | ((unsigned)f2bf(e4m3_rt(v1.y)) << 16);
        o.w = (unsigned)f2bf(e4m3_rt(v1.z)) | ((unsigned)f2bf(e4m3_rt(v1.w)) << 16);
        *(uint4*)(outp + i * 8) = o;
    }
}

// ---------------------------------------------------------------------------
// 256x256 8-phase GEMM, REG-STAGED staging (global->VGPR->swizzled ds_write).
//   Swizzle: physical_chunk16B = logical_chunk ^ (row&7)  [full 3-bit, the
//   only form measured conflict-free: R3/R6 CONF=0 vs 2.517e7 for all others].
//   - Global loads are perfectly LINEAR (lane chunk = tid&7): no source
//     permutation -> no FETCH regression (R3/R6's +90MB came from the
//     16B-granularity source perm that global_load_lds's linear DMA forced;
//     reg-staging moves the permutation to the ds_write address, free).
//   - Writes conflict-free by construction: each 8-lane group writes one row,
//     chunks (0..7)^(row&7) = 8 distinct slots = all 32 banks.
//   - Reads: R6's register-lean form (proven correct): per-thread constants
//     q0=(hi^(l15&7))<<4, q1=q0^64; 8 base pointers (matrix x dbuf x quad);
//     fragment deltas m*2048 are immediates. No offset arrays -> no spill.
//   Schedule: R2's 8-phase skeleton. Per phase: {ds_reads | WR unit (data
//   GL'd 4 phases earlier; compiler inserts exact vmcnt) | GL unit reissue}
//   -> BAR -> lgkmcnt(0) -> setprio(1) 16 MFMA setprio(0) -> BAR.
//   Occupancy is LDS-capped at 1 block/CU (128KiB of 160), so
//   __launch_bounds__(512,1) frees up to 256 VGPRs at zero occupancy cost.
// ---------------------------------------------------------------------------

__global__ __launch_bounds__(512, 1)
void gemm_8ph_kernel(const unsigned short* __restrict__ A,
                     const unsigned short* __restrict__ Bw,
                     const float* __restrict__ bias,
                     float* __restrict__ C) {
    extern __shared__ char smem[];   // 131072 bytes

    // T1: XCD-aware swizzle (512 wgs % 8 == 0)
    int bid = blockIdx.x;
    int swz = (bid & 7) * 64 + (bid >> 3);
    int bm0 = (swz >> 4) * 256;   // 32 M-tiles
    int bn0 = (swz & 15) * 256;   // 16 N-tiles

    int tid = threadIdx.x;
    int l   = tid & 63;
    int w   = tid >> 6;     // 0..7
    int wr  = w >> 2;       // 0..1
    int wc  = w & 3;        // 0..3
    int l15 = l & 15;
    int hi  = l >> 4;       // 0..3

    // ---- Read pointers (swizzled): addr = P[mat][d][q] + frag*2048 (imm).
    unsigned q0 = (unsigned)((hi ^ (l15 & 7)) << 4);
    unsigned q1 = q0 ^ 64u;
    const char* pA0q0 = smem + (unsigned)((wr * 128 + l15) * 128) + q0;
    const char* pA0q1 = pA0q0 + (q1 - q0);
    const char* pB0q0 = smem + 32768u + (unsigned)((wc * 64 + l15) * 128) + q0;
    const char* pB0q1 = pB0q0 + (q1 - q0);
    const char* pA1q0 = pA0q0 + 65536;
    const char* pA1q1 = pA0q1 + 65536;
    const char* pB1q0 = pB0q0 + 65536;
    const char* pB1q1 = pB0q1 + 65536;

    // ---- Write pointers (swizzled): lane's slot within its unit.
    //   row_in_unit = tid>>3 (64 rows per load, but unit spans w*8+(l>>3));
    //   logical chunk = tid&7; physical chunk = (tid&7) ^ ((tid>>3)&7).
    unsigned wbase = (unsigned)(w * 1024 + (l >> 3) * 128 +
                                (((l & 7) ^ (l >> 3)) * 16));
    char* pW0 = smem + wbase;            // d=0; imm adds: B+32768, h*16384, j*8192
    char* pW1 = pW0 + 65536;             // d=1

    // ---- Linear global unit addresses: unit (h,j): rows h*128+j*64+(tid>>3),
    //      lane chunk (tid&7)*8 elements.
    const unsigned short* gA[4];
    const unsigned short* gB[4];
#pragma unroll
    for (int h = 0; h < 2; ++h)
#pragma unroll
        for (int j = 0; j < 2; ++j) {
            int r = h * 128 + j * 64 + (tid >> 3);
            gA[h * 2 + j] = A  + (size_t)(bm0 + r) * K_DIM + (tid & 7) * 8;
            gB[h * 2 + j] = Bw + (size_t)(bn0 + r) * K_DIM + (tid & 7) * 8;
        }

    uint4 rA[2][2], rB[2][2];   // staging regs: [h][j], literal-indexed only

#define GLA(h, kt) do { \
    rA[h][0] = *(const uint4*)(gA[(h)*2+0] + (kt)); \
    rA[h][1] = *(const uint4*)(gA[(h)*2+1] + (kt)); } while (0)
#define GLB(h, kt) do { \
    rB[h][0] = *(const uint4*)(gB[(h)*2+0] + (kt)); \
    rB[h][1] = *(const uint4*)(gB[(h)*2+1] + (kt)); } while (0)
#define WRA(d, h) do { \
    *(uint4*)(((d) ? pW1 : pW0) + (h)*16384 + 0)    = rA[h][0]; \
    *(uint4*)(((d) ? pW1 : pW0) + (h)*16384 + 8192) = rA[h][1]; } while (0)
#define WRB(d, h) do { \
    *(uint4*)(((d) ? pW1 : pW0) + 32768 + (h)*16384 + 0)    = rB[h][0]; \
    *(uint4*)(((d) ? pW1 : pW0) + 32768 + (h)*16384 + 8192) = rB[h][1]; } while (0)

    short8 a[4][2], b0f[2][2], b1f[2][2];
    f32x4 acc[8][4];
#pragma unroll
    for (int m = 0; m < 8; ++m)
#pragma unroll
        for (int n = 0; n < 4; ++n)
            acc[m][n] = (f32x4){0.f, 0.f, 0.f, 0.f};

    auto RDA = [&](int d, int mbase) {
        const char* p0 = d ? pA1q0 : pA0q0;
        const char* p1 = d ? pA1q1 : pA0q1;
#pragma unroll
        for (int m = 0; m < 4; ++m) {
            a[m][0] = *(const short8*)(p0 + (mbase + m) * 2048);
            a[m][1] = *(const short8*)(p1 + (mbase + m) * 2048);
        }
    };
    auto RDB = [&](int d, int nbase, short8 (&bf)[2][2]) {
        const char* p0 = d ? pB1q0 : pB0q0;
        const char* p1 = d ? pB1q1 : pB0q1;
#pragma unroll
        for (int n = 0; n < 2; ++n) {
            bf[n][0] = *(const short8*)(p0 + (nbase + n) * 2048);
            bf[n][1] = *(const short8*)(p1 + (nbase + n) * 2048);
        }
    };
    auto MM = [&](int mbase, int nbase, short8 (&bf)[2][2]) {
        __builtin_amdgcn_s_setprio(1);
#pragma unroll
        for (int m = 0; m < 4; ++m)
#pragma unroll
            for (int n = 0; n < 2; ++n)
#pragma unroll
                for (int q = 0; q < 2; ++q)
                    acc[mbase + m][nbase + n] = __builtin_amdgcn_mfma_f32_16x16x32_bf16(
                        a[m][q], bf[n][q], acc[mbase + m][nbase + n], 0, 0, 0);
        __builtin_amdgcn_s_setprio(0);
    };

    // ---- Prologue: tile0 -> buf0; tile1.B -> buf1; leave in flight:
    //      rA = A(tile1), rB = B(tile2)  [consumed at iter0 ph1/2 and ph3/4].
    GLA(0, 0); GLA(1, 0); GLB(0, 0); GLB(1, 0);
    WRA(0, 0); WRA(0, 1); WRB(0, 0); WRB(0, 1);     // tile0 (auto vmcnt)
    GLB(0, 64); GLB(1, 64);
    WRB(1, 0); WRB(1, 1);                           // tile1 B
    GLA(0, 64); GLA(1, 64);                         // tile1 A  (in flight)
    GLB(0, 128); GLB(1, 128);                       // tile2 B  (in flight)
    asm volatile("s_waitcnt lgkmcnt(0)" ::: "memory");
    BAR();

    // ---- Main loop: 31 iterations, tiles 2i (buf0) and 2i+1 (buf1).
    for (int i = 0; i < 31; ++i) {
        int k2 = (2 * i + 2) * 64;
        int k3 = (2 * i + 3) * 64;
        int k4 = (i < 30) ? (2 * i + 4) * 64 : 0;   // clamp final (dead data)
        // ph1: WR A(2i+1,h0)->buf1 | GL A(2i+2,h0)
        RDA(0, 0); RDB(0, 0, b0f); WRA(1, 0); GLA(0, k2);
        BAR(); WAITK(); MM(0, 0, b0f); BAR();
        // ph2
        RDB(0, 2, b1f); WRA(1, 1); GLA(1, k2);
        BAR(); WAITK(); MM(0, 2, b1f); BAR();
        // ph3: WR B(2i+2,h0)->buf0 | GL B(2i+3,h0)
        RDA(0, 4); WRB(0, 0); GLB(0, k3);
        BAR(); WAITK(); MM(4, 0, b0f); BAR();
        // ph4
        WRB(0, 1); GLB(1, k3);
        BAR(); WAITK(); MM(4, 2, b1f); BAR();
        // ph5: WR A(2i+2,h0)->buf0 | GL A(2i+3,h0)
        RDA(1, 0); RDB(1, 0, b0f); WRA(0, 0); GLA(0, k3);
        BAR(); WAITK(); MM(0, 0, b0f); BAR();
        // ph6
        RDB(1, 2, b1f); WRA(0, 1); GLA(1, k3);
        BAR(); WAITK(); MM(0, 2, b1f); BAR();
        // ph7: WR B(2i+3,h0)->buf1 | GL B(2i+4,h0)
        RDA(1, 4); WRB(1, 0); GLB(0, k4);
        BAR(); WAITK(); MM(4, 0, b0f); BAR();
        // ph8
        WRB(1, 1); GLB(1, k4);
        BAR(); WAITK(); MM(4, 2, b1f); BAR();
    }

    // ---- Peel (tiles 62 buf0, 63 buf1): A(63) written ph1/2 from in-flight.
    {
        RDA(0, 0); RDB(0, 0, b0f); WRA(1, 0);
        BAR(); WAITK(); MM(0, 0, b0f); BAR();
        RDB(0, 2, b1f); WRA(1, 1);
        BAR(); WAITK(); MM(0, 2, b1f); BAR();
        RDA(0, 4);
        BAR(); WAITK(); MM(4, 0, b0f); BAR();
        BAR(); WAITK(); MM(4, 2, b1f); BAR();
        RDA(1, 0); RDB(1, 0, b0f);
        BAR(); WAITK(); MM(0, 0, b0f); BAR();
        RDB(1, 2, b1f);
        BAR(); WAITK(); MM(0, 2, b1f); BAR();
        RDA(1, 4);
        BAR(); WAITK(); MM(4, 0, b0f); BAR();
        BAR(); WAITK(); MM(4, 2, b1f); BAR();
    }

    // ---- Epilogue: C/D layout col=l&15, row=(l>>4)*4+reg. Quantized bias.
    float bq[4];
#pragma unroll
    for (int n = 0; n < 4; ++n)
        bq[n] = e4m3_rt(bias[bn0 + wc * 64 + n * 16 + l15]);

#pragma unroll
    for (int m = 0; m < 8; ++m) {
        int orow = bm0 + wr * 128 + m * 16 + hi * 4;
#pragma unroll
        for (int n = 0; n < 4; ++n) {
            int ocol = bn0 + wc * 64 + n * 16 + l15;
#pragma unroll
            for (int j = 0; j < 4; ++j)
                C[(size_t)(orow + j) * N_DIM + ocol] = acc[m][n][j] + bq[n];
        }
    }
#undef GLA
#undef GLB
#undef WRA
#undef WRB
}

// ---------------------------------------------------------------------------
// Fallback (ws too small): simple fp32 LDS-tiled GEMM. Correctness insurance.
// ---------------------------------------------------------------------------

__global__ void fb_gemm_kernel(const float* __restrict__ A, const float* __restrict__ W,
                               const float* __restrict__ bias, float* __restrict__ C) {
    __shared__ float As[16][16];
    __shared__ float Ws[16][16];
    int tx = threadIdx.x & 15, ty = threadIdx.x >> 4;
    int row = blockIdx.y * 16 + ty;
    int col = blockIdx.x * 16 + tx;
    float acc = 0.f;
    for (int k0 = 0; k0 < K_DIM; k0 += 16) {
        As[ty][tx] = A[(size_t)row * K_DIM + k0 + tx];
        Ws[ty][tx] = e4m3_rt(W[(size_t)(blockIdx.x * 16 + ty) * K_DIM + k0 + tx]);
        __syncthreads();
#pragma unroll
        for (int kk = 0; kk < 16; ++kk)
            acc += As[ty][kk] * Ws[tx][kk];
        __syncthreads();
    }
    C[(size_t)row * N_DIM + col] = acc + e4m3_rt(bias[col]);
}

// ---------------------------------------------------------------------------

extern "C" void kernel_launch(void* const* d_in, const int* in_sizes, int n_in,
                              void* d_out, int out_size, void* d_ws, size_t ws_size,
                              hipStream_t stream) {
    const float* x  = (const float*)d_in[0];   // [8192, 4096] fp32
    const float* wt = (const float*)d_in[1];   // [4096, 4096] fp32
    const float* bi = (const float*)d_in[2];   // [4096] fp32
    float* out = (float*)d_out;

    const size_t needA = (size_t)M_DIM * K_DIM * 2;
    const size_t needW = (size_t)N_DIM * K_DIM * 2;

    if (ws_size >= needA + needW) {
        unsigned short* Abf = (unsigned short*)d_ws;
        unsigned short* Wbf = (unsigned short*)((char*)d_ws + needA);

        cvt_x_kernel<<<2048, 256, 0, stream>>>(x, Abf, (long)M_DIM * K_DIM / 8);
        cvt_w_kernel<<<2048, 256, 0, stream>>>(wt, Wbf, (long)N_DIM * K_DIM / 8);

        (void)hipFuncSetAttribute((const void*)gemm_8ph_kernel,
                                  hipFuncAttributeMaxDynamicSharedMemorySize, 131072);

        dim3 grid((M_DIM / 256) * (N_DIM / 256));  // 512
        gemm_8ph_kernel<<<grid, 512, 131072, stream>>>(Abf, Wbf, bi, out);
    } else {
        dim3 grid(N_DIM / 16, M_DIM / 16);
        fb_gemm_kernel<<<grid, 256, 0, stream>>>(x, wt, bi, out);
    }
}

// Round 9
// 585.369 us; speedup vs baseline: 1.6434x; 1.6434x over previous
//
#include <hip/hip_runtime.h>

// Problem constants (fixed shape)
#define M_DIM 8192   // B*S = 2*4096
#define N_DIM 4096   // D_OUT
#define K_DIM 4096   // D_IN

typedef __attribute__((ext_vector_type(4))) float f32x4;
using short8 = __attribute__((ext_vector_type(8))) short;

// ---------------------------------------------------------------------------
// Numerics helpers
// ---------------------------------------------------------------------------

__device__ __forceinline__ float e4m3_rt(float f) {
    float a = fabsf(f);
    int e = (int)((__float_as_uint(a) >> 23)) - 127;
    if (e < -6) e = -6;
    float q    = __uint_as_float((unsigned)(e - 3 + 127) << 23);
    float qinv = __uint_as_float((unsigned)(3 - e + 127) << 23);
    float r = rintf(a * qinv) * q;
    if (r > 448.0f) r = 448.0f;
    return copysignf(r, f);
}

__device__ __forceinline__ unsigned short f2bf(float f) {
    unsigned u = __float_as_uint(f);
    u += 0x7FFFu + ((u >> 16) & 1u);
    return (unsigned short)(u >> 16);
}

#define BAR()   asm volatile("s_barrier" ::: "memory")
#define WAITK() do { asm volatile("s_waitcnt lgkmcnt(0)" ::: "memory"); \
                     __builtin_amdgcn_sched_barrier(0); } while (0)

// ---------------------------------------------------------------------------
// Conversion pre-passes (unchanged)
// ---------------------------------------------------------------------------

__global__ void cvt_x_kernel(const float* __restrict__ in,
                             unsigned short* __restrict__ outp, long n8) {
    long stride = (long)gridDim.x * blockDim.x;
    for (long i = (long)blockIdx.x * blockDim.x + threadIdx.x; i < n8; i += stride) {
        const float4* p = (const float4*)(in + i * 8);
        float4 v0 = p[0], v1 = p[1];
        uint4 o;
        o.x = (unsigned)f2bf(v0.x) | ((unsigned)f2bf(v0.y) << 16);
        o.y = (unsigned)f2bf(v0.z) | ((unsigned)f2bf(v0.w) << 16);
        o.z = (unsigned)f2bf(v1.x) | ((unsigned)f2bf(v1.y) << 16);
        o.w = (unsigned)f2bf(v1.z) | ((unsigned)f2bf(v1.w) << 16);
        *(uint4*)(outp + i * 8) = o;
    }
}

__global__ void cvt_w_kernel(const float* __restrict__ in,
                             unsigned short* __restrict__ outp, long n8) {
    long stride = (long)gridDim.x * blockDim.x;
    for (long i = (long)blockIdx.x * blockDim.x + threadIdx.x; i < n8; i += stride) {
        const float4* p = (const float4*)(in + i * 8);
        float4 v0 = p[0], v1 = p[1];
        uint4 o;
        o.x = (unsigned)f2bf(e4m3_rt(v0.x)) | ((unsigned)f2bf(e4m3_rt(v0.y)) << 16);
        o.y = (unsigned)f2bf(e4m3_rt(v0.z)) | ((unsigned)f2bf(e4m3_rt(v0.w)) << 16);
        o.z = (unsigned)f2bf(e4m3_rt(v1.x)) | ((unsigned)f2bf(e4m3_rt(v1.y)) << 16);
        o.w = (unsigned)f2bf(e4m3_rt(v1.z)) | ((unsigned)f2bf(e4m3_rt(v1.w)) << 16);
        *(uint4*)(outp + i * 8) = o;
    }
}

// ---------------------------------------------------------------------------
// 256x256 8-phase GEMM, lean reg-staged (R8 structure, spill-free).
//   - Linear global loads (no source perm -> clean FETCH).
//   - Full bit-4 write swizzle: physical_chunk = chunk ^ (row&7). Reads use
//     q0=(hi^(l15&7))<<4, q1=q0^64 (R8-verified, CONF=0).
//   - Staging: TWO 8-reg sets (S1 odd phases, S2 even), GL at phase p ->
//     ds_write at p+2 on the same set; each WR immediately precedes the
//     set's next GL so live ranges chain instead of stacking. 16 staging
//     regs total (R8 had 32 held 4 phases -> spilled 1.04 GB of scratch).
//   Unit chain (iter i), verified closed across iterations:
//     S1: GL ph1 A1(2i+1)->WR ph3 | GL ph3 B1(2i+2)->WR ph5 |
//         GL ph5 A1(2i+2)->WR ph7 | GL ph7 B1(2i+3)->WR ph1(i+1)
//     S2: GL ph2 B0(2i+2)->WR ph4 | GL ph4 A0(2i+2)->WR ph6 |
//         GL ph6 B0(2i+3)->WR ph8 | GL ph8 A0(2i+3)->WR ph2(i+1)
//   Buffer-free windows all respected (buf.B free after ph2/ph6 reads,
//   buf.A after ph3/ph7; every WR lands after the free and before the
//   consuming read). Write visibility: WR -> BAR -> lgkmcnt(0) (own-queue
//   drain) -> BAR2 orders it before any other wave's next-phase reads.
// ---------------------------------------------------------------------------

__global__ __launch_bounds__(512, 1)
void gemm_8ph_kernel(const unsigned short* __restrict__ A,
                     const unsigned short* __restrict__ Bw,
                     const float* __restrict__ bias,
                     float* __restrict__ C) {
    extern __shared__ char smem[];   // 131072 bytes

    // T1: XCD-aware swizzle (512 wgs % 8 == 0)
    int bid = blockIdx.x;
    int swz = (bid & 7) * 64 + (bid >> 3);
    int bm0 = (swz >> 4) * 256;   // 32 M-tiles
    int bn0 = (swz & 15) * 256;   // 16 N-tiles

    int tid = threadIdx.x;
    int l   = tid & 63;
    int w   = tid >> 6;     // 0..7
    int wr  = w >> 2;       // 0..1
    int wc  = w & 3;        // 0..3
    int l15 = l & 15;
    int hi  = l >> 4;       // 0..3

    // ---- Read pointers (swizzled, R8-verified): addr = P + frag*2048 (imm).
    unsigned q0 = (unsigned)((hi ^ (l15 & 7)) << 4);
    unsigned q1 = q0 ^ 64u;
    const char* pA0q0 = smem + (unsigned)((wr * 128 + l15) * 128) + q0;
    const char* pA0q1 = smem + (unsigned)((wr * 128 + l15) * 128) + q1;
    const char* pB0q0 = smem + 32768u + (unsigned)((wc * 64 + l15) * 128) + q0;
    const char* pB0q1 = smem + 32768u + (unsigned)((wc * 64 + l15) * 128) + q1;
    const char* pA1q0 = pA0q0 + 65536;
    const char* pA1q1 = pA0q1 + 65536;
    const char* pB1q0 = pB0q0 + 65536;
    const char* pB1q1 = pB0q1 + 65536;

    // ---- Write pointers (swizzled): physical chunk = (l&7) ^ ((tid>>3)&7).
    unsigned wbase = (unsigned)(w * 1024 + (l >> 3) * 128 +
                                (((l & 7) ^ (l >> 3)) * 16));
    char* pW0 = smem + wbase;            // imm adds: isB*32768 + h*16384 + j*8192
    char* pW1 = pW0 + 65536;

    // ---- Linear global bases (per-thread row tid>>3, chunk tid&7).
    const unsigned short* gA0 = A  + (size_t)(bm0 + (tid >> 3)) * K_DIM + (tid & 7) * 8;
    const unsigned short* gB0 = Bw + (size_t)(bn0 + (tid >> 3)) * K_DIM + (tid & 7) * 8;

    uint4 S1[2], S2[2];   // staging sets (literal-indexed only)

#define GLS(S, G, h, kt) do { \
    S[0] = *(const uint4*)((G) + (size_t)((h) * 128 +  0) * K_DIM + (kt)); \
    S[1] = *(const uint4*)((G) + (size_t)((h) * 128 + 64) * K_DIM + (kt)); } while (0)
#define WRS(S, d, isB, h) do { \
    *(uint4*)(((d) ? pW1 : pW0) + (isB) * 32768 + (h) * 16384 +    0) = S[0]; \
    *(uint4*)(((d) ? pW1 : pW0) + (isB) * 32768 + (h) * 16384 + 8192) = S[1]; } while (0)

    short8 a[4][2], b0f[2][2], b1f[2][2];
    f32x4 acc[8][4];
#pragma unroll
    for (int m = 0; m < 8; ++m)
#pragma unroll
        for (int n = 0; n < 4; ++n)
            acc[m][n] = (f32x4){0.f, 0.f, 0.f, 0.f};

    auto RDA = [&](int d, int mbase) {
        const char* p0 = d ? pA1q0 : pA0q0;
        const char* p1 = d ? pA1q1 : pA0q1;
#pragma unroll
        for (int m = 0; m < 4; ++m) {
            a[m][0] = *(const short8*)(p0 + (mbase + m) * 2048);
            a[m][1] = *(const short8*)(p1 + (mbase + m) * 2048);
        }
    };
    auto RDB = [&](int d, int nbase, short8 (&bf)[2][2]) {
        const char* p0 = d ? pB1q0 : pB0q0;
        const char* p1 = d ? pB1q1 : pB0q1;
#pragma unroll
        for (int n = 0; n < 2; ++n) {
            bf[n][0] = *(const short8*)(p0 + (nbase + n) * 2048);
            bf[n][1] = *(const short8*)(p1 + (nbase + n) * 2048);
        }
    };
    auto MM = [&](int mbase, int nbase, short8 (&bf)[2][2]) {
        __builtin_amdgcn_s_setprio(1);
#pragma unroll
        for (int m = 0; m < 4; ++m)
#pragma unroll
            for (int n = 0; n < 2; ++n)
#pragma unroll
                for (int q = 0; q < 2; ++q)
                    acc[mbase + m][nbase + n] = __builtin_amdgcn_mfma_f32_16x16x32_bf16(
                        a[m][q], bf[n][q], acc[mbase + m][nbase + n], 0, 0, 0);
        __builtin_amdgcn_s_setprio(0);
    };

    // ---- Prologue: buf0 <- tile0 (A,B); buf1 <- B0(1); then preload the
    //      chain heads: S1 = B1(1) (WR @ iter0.ph1), S2 = A0(1) (WR @ ph2).
    GLS(S1, gA0, 0, 0);  GLS(S2, gA0, 1, 0);
    WRS(S1, 0, 0, 0);    WRS(S2, 0, 0, 1);
    GLS(S1, gB0, 0, 0);  GLS(S2, gB0, 1, 0);
    WRS(S1, 0, 1, 0);    WRS(S2, 0, 1, 1);
    GLS(S1, gB0, 0, 64); WRS(S1, 1, 1, 0);      // B0(1) -> buf1
    GLS(S1, gB0, 1, 64);                        // S1 = B1(1)
    GLS(S2, gA0, 0, 64);                        // S2 = A0(1)
    asm volatile("s_waitcnt lgkmcnt(0)" ::: "memory");
    BAR();

    // ---- Main loop: 31 iterations, tiles 2i (buf0, ph1-4), 2i+1 (buf1, ph5-8).
    for (int i = 0; i < 31; ++i) {
        int k1 = (2 * i + 1) * 64, k2 = (2 * i + 2) * 64, k3 = (2 * i + 3) * 64;
        // ph1: WR B1(2i+1)->buf1 | GL A1(2i+1)
        RDA(0, 0); RDB(0, 0, b0f); WRS(S1, 1, 1, 1); GLS(S1, gA0, 1, k1);
        BAR(); WAITK(); MM(0, 0, b0f); BAR();
        // ph2: WR A0(2i+1)->buf1 | GL B0(2i+2)
        RDB(0, 2, b1f); WRS(S2, 1, 0, 0); GLS(S2, gB0, 0, k2);
        BAR(); WAITK(); MM(0, 2, b1f); BAR();
        // ph3: WR A1(2i+1)->buf1 | GL B1(2i+2)
        RDA(0, 4); WRS(S1, 1, 0, 1); GLS(S1, gB0, 1, k2);
        BAR(); WAITK(); MM(4, 0, b0f); BAR();
        // ph4: WR B0(2i+2)->buf0 | GL A0(2i+2)
        WRS(S2, 0, 1, 0); GLS(S2, gA0, 0, k2);
        BAR(); WAITK(); MM(4, 2, b1f); BAR();
        // ph5: WR B1(2i+2)->buf0 | GL A1(2i+2)
        RDA(1, 0); RDB(1, 0, b0f); WRS(S1, 0, 1, 1); GLS(S1, gA0, 1, k2);
        BAR(); WAITK(); MM(0, 0, b0f); BAR();
        // ph6: WR A0(2i+2)->buf0 | GL B0(2i+3)
        RDB(1, 2, b1f); WRS(S2, 0, 0, 0); GLS(S2, gB0, 0, k3);
        BAR(); WAITK(); MM(0, 2, b1f); BAR();
        // ph7: WR A1(2i+2)->buf0 | GL B1(2i+3)
        RDA(1, 4); WRS(S1, 0, 0, 1); GLS(S1, gB0, 1, k3);
        BAR(); WAITK(); MM(4, 0, b0f); BAR();
        // ph8: WR B0(2i+3)->buf1 | GL A0(2i+3)
        WRS(S2, 1, 1, 0); GLS(S2, gA0, 0, k3);
        BAR(); WAITK(); MM(4, 2, b1f); BAR();
    }

    // ---- Peel (tiles 62=buf0, 63=buf1). Entering: S1=B1(63), S2=A0(63).
    {
        int k1 = 63 * 64;
        RDA(0, 0); RDB(0, 0, b0f); WRS(S1, 1, 1, 1); GLS(S1, gA0, 1, k1);
        BAR(); WAITK(); MM(0, 0, b0f); BAR();
        RDB(0, 2, b1f); WRS(S2, 1, 0, 0);
        BAR(); WAITK(); MM(0, 2, b1f); BAR();
        RDA(0, 4); WRS(S1, 1, 0, 1);
        BAR(); WAITK(); MM(4, 0, b0f); BAR();
        BAR(); WAITK(); MM(4, 2, b1f); BAR();
        RDA(1, 0); RDB(1, 0, b0f);
        BAR(); WAITK(); MM(0, 0, b0f); BAR();
        RDB(1, 2, b1f);
        BAR(); WAITK(); MM(0, 2, b1f); BAR();
        RDA(1, 4);
        BAR(); WAITK(); MM(4, 0, b0f); BAR();
        BAR(); WAITK(); MM(4, 2, b1f); BAR();
    }

    // ---- Epilogue: C/D layout col=l&15, row=(l>>4)*4+reg. Quantized bias.
    float bq[4];
#pragma unroll
    for (int n = 0; n < 4; ++n)
        bq[n] = e4m3_rt(bias[bn0 + wc * 64 + n * 16 + l15]);

#pragma unroll
    for (int m = 0; m < 8; ++m) {
        int orow = bm0 + wr * 128 + m * 16 + hi * 4;
#pragma unroll
        for (int n = 0; n < 4; ++n) {
            int ocol = bn0 + wc * 64 + n * 16 + l15;
#pragma unroll
            for (int j = 0; j < 4; ++j)
                C[(size_t)(orow + j) * N_DIM + ocol] = acc[m][n][j] + bq[n];
        }
    }
#undef GLS
#undef WRS
}

// ---------------------------------------------------------------------------
// Fallback (ws too small): simple fp32 LDS-tiled GEMM. Correctness insurance.
// ---------------------------------------------------------------------------

__global__ void fb_gemm_kernel(const float* __restrict__ A, const float* __restrict__ W,
                               const float* __restrict__ bias, float* __restrict__ C) {
    __shared__ float As[16][16];
    __shared__ float Ws[16][16];
    int tx = threadIdx.x & 15, ty = threadIdx.x >> 4;
    int row = blockIdx.y * 16 + ty;
    int col = blockIdx.x * 16 + tx;
    float acc = 0.f;
    for (int k0 = 0; k0 < K_DIM; k0 += 16) {
        As[ty][tx] = A[(size_t)row * K_DIM + k0 + tx];
        Ws[ty][tx] = e4m3_rt(W[(size_t)(blockIdx.x * 16 + ty) * K_DIM + k0 + tx]);
        __syncthreads();
#pragma unroll
        for (int kk = 0; kk < 16; ++kk)
            acc += As[ty][kk] * Ws[tx][kk];
        __syncthreads();
    }
    C[(size_t)row * N_DIM + col] = acc + e4m3_rt(bias[col]);
}

// ---------------------------------------------------------------------------

extern "C" void kernel_launch(void* const* d_in, const int* in_sizes, int n_in,
                              void* d_out, int out_size, void* d_ws, size_t ws_size,
                              hipStream_t stream) {
    const float* x  = (const float*)d_in[0];   // [8192, 4096] fp32
    const float* wt = (const float*)d_in[1];   // [4096, 4096] fp32
    const float* bi = (const float*)d_in[2];   // [4096] fp32
    float* out = (float*)d_out;

    const size_t needA = (size_t)M_DIM * K_DIM * 2;
    const size_t needW = (size_t)N_DIM * K_DIM * 2;

    if (ws_size >= needA + needW) {
        unsigned short* Abf = (unsigned short*)d_ws;
        unsigned short* Wbf = (unsigned short*)((char*)d_ws + needA);

        cvt_x_kernel<<<2048, 256, 0, stream>>>(x, Abf, (long)M_DIM * K_DIM / 8);
        cvt_w_kernel<<<2048, 256, 0, stream>>>(wt, Wbf, (long)N_DIM * K_DIM / 8);

        (void)hipFuncSetAttribute((const void*)gemm_8ph_kernel,
                                  hipFuncAttributeMaxDynamicSharedMemorySize, 131072);

        dim3 grid((M_DIM / 256) * (N_DIM / 256));  // 512
        gemm_8ph_kernel<<<grid, 512, 131072, stream>>>(Abf, Wbf, bi, out);
    } else {
        dim3 grid(N_DIM / 16, M_DIM / 16);
        fb_gemm_kernel<<<grid, 256, 0, stream>>>(x, wt, bi, out);
    }
}

// Round 10
// 469.556 us; speedup vs baseline: 2.0488x; 1.2466x over previous
//
#include <hip/hip_runtime.h>

// Problem constants (fixed shape)
#define M_DIM 8192   // B*S = 2*4096
#define N_DIM 4096   // D_OUT
#define K_DIM 4096   // D_IN

typedef __attribute__((ext_vector_type(4))) float f32x4;
using short8 = __attribute__((ext_vector_type(8))) short;

// ---------------------------------------------------------------------------
// Numerics helpers
// ---------------------------------------------------------------------------

__device__ __forceinline__ float e4m3_rt(float f) {
    float a = fabsf(f);
    int e = (int)((__float_as_uint(a) >> 23)) - 127;
    if (e < -6) e = -6;
    float q    = __uint_as_float((unsigned)(e - 3 + 127) << 23);
    float qinv = __uint_as_float((unsigned)(3 - e + 127) << 23);
    float r = rintf(a * qinv) * q;
    if (r > 448.0f) r = 448.0f;
    return copysignf(r, f);
}

__device__ __forceinline__ unsigned short f2bf(float f) {
    unsigned u = __float_as_uint(f);
    u += 0x7FFFu + ((u >> 16) & 1u);
    return (unsigned short)(u >> 16);
}

#define BAR()   asm volatile("s_barrier" ::: "memory")
#define WAITK() do { asm volatile("s_waitcnt lgkmcnt(0)" ::: "memory"); \
                     __builtin_amdgcn_sched_barrier(0); } while (0)

// ---------------------------------------------------------------------------
// Conversion pre-passes (unchanged)
// ---------------------------------------------------------------------------

__global__ void cvt_x_kernel(const float* __restrict__ in,
                             unsigned short* __restrict__ outp, long n8) {
    long stride = (long)gridDim.x * blockDim.x;
    for (long i = (long)blockIdx.x * blockDim.x + threadIdx.x; i < n8; i += stride) {
        const float4* p = (const float4*)(in + i * 8);
        float4 v0 = p[0], v1 = p[1];
        uint4 o;
        o.x = (unsigned)f2bf(v0.x) | ((unsigned)f2bf(v0.y) << 16);
        o.y = (unsigned)f2bf(v0.z) | ((unsigned)f2bf(v0.w) << 16);
        o.z = (unsigned)f2bf(v1.x) | ((unsigned)f2bf(v1.y) << 16);
        o.w = (unsigned)f2bf(v1.z) | ((unsigned)f2bf(v1.w) << 16);
        *(uint4*)(outp + i * 8) = o;
    }
}

__global__ void cvt_w_kernel(const float* __restrict__ in,
                             unsigned short* __restrict__ outp, long n8) {
    long stride = (long)gridDim.x * blockDim.x;
    for (long i = (long)blockIdx.x * blockDim.x + threadIdx.x; i < n8; i += stride) {
        const float4* p = (const float4*)(in + i * 8);
        float4 v0 = p[0], v1 = p[1];
        uint4 o;
        o.x = (unsigned)f2bf(e4m3_rt(v0.x)) | ((unsigned)f2bf(e4m3_rt(v0.y)) << 16);
        o.y = (unsigned)f2bf(e4m3_rt(v0.z)) | ((unsigned)f2bf(e4m3_rt(v0.w)) << 16);
        o.z = (unsigned)f2bf(e4m3_rt(v1.x)) | ((unsigned)f2bf(e4m3_rt(v1.y)) << 16);
        o.w = (unsigned)f2bf(e4m3_rt(v1.z)) | ((unsigned)f2bf(e4m3_rt(v1.w)) << 16);
        *(uint4*)(outp + i * 8) = o;
    }
}

// ---------------------------------------------------------------------------
// 256x256 8-phase GEMM, single-set reg staging (spill-free by construction).
//   - Linear global loads (clean FETCH), full bit-4 write swizzle
//     (physical_chunk = chunk ^ (row&7); CONF=0, R8/R9-verified), R9 read
//     addressing verbatim.
//   - Staging: ONE 8-reg set S. GL at phase p -> ds_write at p+1 (compiler
//     inserts the exact vmcnt before the write). 8 units/iter:
//       ph1 WR B1(2i+1)  GL A0(2i+1)   | ph2 WR A0(2i+1)  GL A1(2i+1)
//       ph3 WR A1(2i+1)  GL B0(2i+2)   | ph4 WR B0(2i+2)  GL B1(2i+2)
//       ph5 WR B1(2i+2)  GL A0(2i+2)   | ph6 WR A0(2i+2)  GL A1(2i+2)
//       ph7 WR A1(2i+2)  GL B0(2i+3)   | ph8 WR B0(2i+3)  GL B1(2i+3)
//     Buffer windows audited: buf0.B reads end ph2 (writes ph4/5), buf0.A
//     reads end ph3 (writes ph6/7), buf1.B reads end ph6 (writes ph8/ph1'),
//     buf1.A reads end ph7 (writes ph2'/ph3'). Write visibility: WR -> BAR
//     -> lgkmcnt(0) -> BAR before any cross-wave read (R9 mechanism).
//   - Register ledger: acc 128 AGPR (hard 128-arch cap for 8-wave blocks,
//     m69 law) + A-frags 32 + B-frags 32 + S 8 + ptrs ~24 + temps < 128.
//     R9's 16-reg staging was ~8 regs over -> 276 MB spill; this fits.
// ---------------------------------------------------------------------------

__global__ __launch_bounds__(512, 1)
void gemm_8ph_kernel(const unsigned short* __restrict__ A,
                     const unsigned short* __restrict__ Bw,
                     const float* __restrict__ bias,
                     float* __restrict__ C) {
    extern __shared__ char smem[];   // 131072 bytes

    // T1: XCD-aware swizzle (512 wgs % 8 == 0)
    int bid = blockIdx.x;
    int swz = (bid & 7) * 64 + (bid >> 3);
    int bm0 = (swz >> 4) * 256;   // 32 M-tiles
    int bn0 = (swz & 15) * 256;   // 16 N-tiles

    int tid = threadIdx.x;
    int l   = tid & 63;
    int w   = tid >> 6;     // 0..7
    int wr  = w >> 2;       // 0..1
    int wc  = w & 3;        // 0..3
    int l15 = l & 15;
    int hi  = l >> 4;       // 0..3

    // ---- Read pointers (swizzled, R8/R9-verified): addr = P + frag*2048.
    unsigned q0 = (unsigned)((hi ^ (l15 & 7)) << 4);
    unsigned q1 = q0 ^ 64u;
    const char* pA0q0 = smem + (unsigned)((wr * 128 + l15) * 128) + q0;
    const char* pA0q1 = smem + (unsigned)((wr * 128 + l15) * 128) + q1;
    const char* pB0q0 = smem + 32768u + (unsigned)((wc * 64 + l15) * 128) + q0;
    const char* pB0q1 = smem + 32768u + (unsigned)((wc * 64 + l15) * 128) + q1;
    const char* pA1q0 = pA0q0 + 65536;
    const char* pA1q1 = pA0q1 + 65536;
    const char* pB1q0 = pB0q0 + 65536;
    const char* pB1q1 = pB0q1 + 65536;

    // ---- Write pointers (swizzled): physical chunk = (l&7) ^ ((tid>>3)&7).
    unsigned wbase = (unsigned)(w * 1024 + (l >> 3) * 128 +
                                (((l & 7) ^ (l >> 3)) * 16));
    char* pW0 = smem + wbase;            // imm adds: isB*32768 + h*16384 + j*8192
    char* pW1 = pW0 + 65536;

    // ---- Linear global bases (per-thread row tid>>3, chunk tid&7).
    const unsigned short* gA0 = A  + (size_t)(bm0 + (tid >> 3)) * K_DIM + (tid & 7) * 8;
    const unsigned short* gB0 = Bw + (size_t)(bn0 + (tid >> 3)) * K_DIM + (tid & 7) * 8;

    uint4 S[2];   // single staging set (literal-indexed only)

#define GLS(G, h, kt) do { \
    S[0] = *(const uint4*)((G) + (size_t)((h) * 128 +  0) * K_DIM + (kt)); \
    S[1] = *(const uint4*)((G) + (size_t)((h) * 128 + 64) * K_DIM + (kt)); } while (0)
#define WRS(d, isB, h) do { \
    *(uint4*)(((d) ? pW1 : pW0) + (isB) * 32768 + (h) * 16384 +    0) = S[0]; \
    *(uint4*)(((d) ? pW1 : pW0) + (isB) * 32768 + (h) * 16384 + 8192) = S[1]; } while (0)

    short8 a[4][2], b0f[2][2], b1f[2][2];
    f32x4 acc[8][4];
#pragma unroll
    for (int m = 0; m < 8; ++m)
#pragma unroll
        for (int n = 0; n < 4; ++n)
            acc[m][n] = (f32x4){0.f, 0.f, 0.f, 0.f};

    auto RDA = [&](int d, int mbase) {
        const char* p0 = d ? pA1q0 : pA0q0;
        const char* p1 = d ? pA1q1 : pA0q1;
#pragma unroll
        for (int m = 0; m < 4; ++m) {
            a[m][0] = *(const short8*)(p0 + (mbase + m) * 2048);
            a[m][1] = *(const short8*)(p1 + (mbase + m) * 2048);
        }
    };
    auto RDB = [&](int d, int nbase, short8 (&bf)[2][2]) {
        const char* p0 = d ? pB1q0 : pB0q0;
        const char* p1 = d ? pB1q1 : pB0q1;
#pragma unroll
        for (int n = 0; n < 2; ++n) {
            bf[n][0] = *(const short8*)(p0 + (nbase + n) * 2048);
            bf[n][1] = *(const short8*)(p1 + (nbase + n) * 2048);
        }
    };
    auto MM = [&](int mbase, int nbase, short8 (&bf)[2][2]) {
        __builtin_amdgcn_s_setprio(1);
#pragma unroll
        for (int m = 0; m < 4; ++m)
#pragma unroll
            for (int n = 0; n < 2; ++n)
#pragma unroll
                for (int q = 0; q < 2; ++q)
                    acc[mbase + m][nbase + n] = __builtin_amdgcn_mfma_f32_16x16x32_bf16(
                        a[m][q], bf[n][q], acc[mbase + m][nbase + n], 0, 0, 0);
        __builtin_amdgcn_s_setprio(0);
    };

    // ---- Prologue: buf0 <- tile0 (A,B); buf1 <- B0(1); S <- B1(1) in flight.
    GLS(gA0, 0, 0);  WRS(0, 0, 0);     // A0(0)
    GLS(gA0, 1, 0);  WRS(0, 0, 1);     // A1(0)
    GLS(gB0, 0, 0);  WRS(0, 1, 0);     // B0(0)
    GLS(gB0, 1, 0);  WRS(0, 1, 1);     // B1(0)
    GLS(gB0, 0, 64); WRS(1, 1, 0);     // B0(1) -> buf1
    GLS(gB0, 1, 64);                   // S = B1(1)
    asm volatile("s_waitcnt lgkmcnt(0)" ::: "memory");
    BAR();

    // ---- Main loop: 31 iterations, tiles 2i (buf0, ph1-4), 2i+1 (buf1, ph5-8).
    for (int i = 0; i < 31; ++i) {
        int k1 = (2 * i + 1) * 64, k2 = (2 * i + 2) * 64, k3 = (2 * i + 3) * 64;
        // ph1: WR B1(2i+1)->buf1 | GL A0(2i+1)
        RDA(0, 0); RDB(0, 0, b0f); WRS(1, 1, 1); GLS(gA0, 0, k1);
        BAR(); WAITK(); MM(0, 0, b0f); BAR();
        // ph2: WR A0(2i+1)->buf1 | GL A1(2i+1)
        RDB(0, 2, b1f); WRS(1, 0, 0); GLS(gA0, 1, k1);
        BAR(); WAITK(); MM(0, 2, b1f); BAR();
        // ph3: WR A1(2i+1)->buf1 | GL B0(2i+2)
        RDA(0, 4); WRS(1, 0, 1); GLS(gB0, 0, k2);
        BAR(); WAITK(); MM(4, 0, b0f); BAR();
        // ph4: WR B0(2i+2)->buf0 | GL B1(2i+2)
        WRS(0, 1, 0); GLS(gB0, 1, k2);
        BAR(); WAITK(); MM(4, 2, b1f); BAR();
        // ph5: WR B1(2i+2)->buf0 | GL A0(2i+2)
        RDA(1, 0); RDB(1, 0, b0f); WRS(0, 1, 1); GLS(gA0, 0, k2);
        BAR(); WAITK(); MM(0, 0, b0f); BAR();
        // ph6: WR A0(2i+2)->buf0 | GL A1(2i+2)
        RDB(1, 2, b1f); WRS(0, 0, 0); GLS(gA0, 1, k2);
        BAR(); WAITK(); MM(0, 2, b1f); BAR();
        // ph7: WR A1(2i+2)->buf0 | GL B0(2i+3)
        RDA(1, 4); WRS(0, 0, 1); GLS(gB0, 0, k3);
        BAR(); WAITK(); MM(4, 0, b0f); BAR();
        // ph8: WR B0(2i+3)->buf1 | GL B1(2i+3)
        WRS(1, 1, 0); GLS(gB0, 1, k3);
        BAR(); WAITK(); MM(4, 2, b1f); BAR();
    }

    // ---- Peel (tiles 62=buf0, 63=buf1). Entering: S = B1(63).
    {
        int k1 = 63 * 64;
        // pph1: WR B1(63)->buf1 | GL A0(63)
        RDA(0, 0); RDB(0, 0, b0f); WRS(1, 1, 1); GLS(gA0, 0, k1);
        BAR(); WAITK(); MM(0, 0, b0f); BAR();
        // pph2: WR A0(63)->buf1 | GL A1(63)
        RDB(0, 2, b1f); WRS(1, 0, 0); GLS(gA0, 1, k1);
        BAR(); WAITK(); MM(0, 2, b1f); BAR();
        // pph3: WR A1(63)->buf1
        RDA(0, 4); WRS(1, 0, 1);
        BAR(); WAITK(); MM(4, 0, b0f); BAR();
        BAR(); WAITK(); MM(4, 2, b1f); BAR();
        RDA(1, 0); RDB(1, 0, b0f);
        BAR(); WAITK(); MM(0, 0, b0f); BAR();
        RDB(1, 2, b1f);
        BAR(); WAITK(); MM(0, 2, b1f); BAR();
        RDA(1, 4);
        BAR(); WAITK(); MM(4, 0, b0f); BAR();
        BAR(); WAITK(); MM(4, 2, b1f); BAR();
    }

    // ---- Epilogue: C/D layout col=l&15, row=(l>>4)*4+reg. Quantized bias.
    float bq[4];
#pragma unroll
    for (int n = 0; n < 4; ++n)
        bq[n] = e4m3_rt(bias[bn0 + wc * 64 + n * 16 + l15]);

#pragma unroll
    for (int m = 0; m < 8; ++m) {
        int orow = bm0 + wr * 128 + m * 16 + hi * 4;
#pragma unroll
        for (int n = 0; n < 4; ++n) {
            int ocol = bn0 + wc * 64 + n * 16 + l15;
#pragma unroll
            for (int j = 0; j < 4; ++j)
                C[(size_t)(orow + j) * N_DIM + ocol] = acc[m][n][j] + bq[n];
        }
    }
#undef GLS
#undef WRS
}

// ---------------------------------------------------------------------------
// Fallback (ws too small): simple fp32 LDS-tiled GEMM. Correctness insurance.
// ---------------------------------------------------------------------------

__global__ void fb_gemm_kernel(const float* __restrict__ A, const float* __restrict__ W,
                               const float* __restrict__ bias, float* __restrict__ C) {
    __shared__ float As[16][16];
    __shared__ float Ws[16][16];
    int tx = threadIdx.x & 15, ty = threadIdx.x >> 4;
    int row = blockIdx.y * 16 + ty;
    int col = blockIdx.x * 16 + tx;
    float acc = 0.f;
    for (int k0 = 0; k0 < K_DIM; k0 += 16) {
        As[ty][tx] = A[(size_t)row * K_DIM + k0 + tx];
        Ws[ty][tx] = e4m3_rt(W[(size_t)(blockIdx.x * 16 + ty) * K_DIM + k0 + tx]);
        __syncthreads();
#pragma unroll
        for (int kk = 0; kk < 16; ++kk)
            acc += As[ty][kk] * Ws[tx][kk];
        __syncthreads();
    }
    C[(size_t)row * N_DIM + col] = acc + e4m3_rt(bias[col]);
}

// ---------------------------------------------------------------------------

extern "C" void kernel_launch(void* const* d_in, const int* in_sizes, int n_in,
                              void* d_out, int out_size, void* d_ws, size_t ws_size,
                              hipStream_t stream) {
    const float* x  = (const float*)d_in[0];   // [8192, 4096] fp32
    const float* wt = (const float*)d_in[1];   // [4096, 4096] fp32
    const float* bi = (const float*)d_in[2];   // [4096] fp32
    float* out = (float*)d_out;

    const size_t needA = (size_t)M_DIM * K_DIM * 2;
    const size_t needW = (size_t)N_DIM * K_DIM * 2;

    if (ws_size >= needA + needW) {
        unsigned short* Abf = (unsigned short*)d_ws;
        unsigned short* Wbf = (unsigned short*)((char*)d_ws + needA);

        cvt_x_kernel<<<2048, 256, 0, stream>>>(x, Abf, (long)M_DIM * K_DIM / 8);
        cvt_w_kernel<<<2048, 256, 0, stream>>>(wt, Wbf, (long)N_DIM * K_DIM / 8);

        (void)hipFuncSetAttribute((const void*)gemm_8ph_kernel,
                                  hipFuncAttributeMaxDynamicSharedMemorySize, 131072);

        dim3 grid((M_DIM / 256) * (N_DIM / 256));  // 512
        gemm_8ph_kernel<<<grid, 512, 131072, stream>>>(Abf, Wbf, bi, out);
    } else {
        dim3 grid(N_DIM / 16, M_DIM / 16);
        fb_gemm_kernel<<<grid, 256, 0, stream>>>(x, wt, bi, out);
    }
}